// Round 1
// baseline (575.816 us; speedup 1.0000x reference)
//
#include <hip/hip_runtime.h>
#include <math.h>

#define TD 128   // feature dimension
#define BT 64    // tile rows per block

// ---------------------------------------------------------------------------
// Kernel 1: per-row squared norms of Z = [X; Y]
// ---------------------------------------------------------------------------
__global__ __launch_bounds__(256) void norms_kernel(const float* __restrict__ X,
                                                    const float* __restrict__ Y,
                                                    int n, int tot,
                                                    float* __restrict__ norms) {
    int r = blockIdx.x * 256 + threadIdx.x;
    if (r >= tot) return;
    const float* row = (r < n) ? (X + (size_t)r * TD) : (Y + (size_t)(r - n) * TD);
    float s = 0.f;
#pragma unroll
    for (int k = 0; k < TD; k += 4) {
        float4 v = *reinterpret_cast<const float4*>(row + k);
        s = fmaf(v.x, v.x, s);
        s = fmaf(v.y, v.y, s);
        s = fmaf(v.z, v.z, s);
        s = fmaf(v.w, v.w, s);
    }
    norms[r] = s;
}

// ---------------------------------------------------------------------------
// Kernel 2: one 64x64 tile of the symmetric pair-matrix per block.
// Triangular grid: only bj >= bi tiles; off-diagonal tiles weighted 2x.
// LDS tiles stored k-major [128][64] so fragment reads are ds_read_b128
// with broadcast addresses (conflict-free); staging transposed writes are
// 2-way bank aliased (free).
// ---------------------------------------------------------------------------
__global__ __launch_bounds__(256, 2) void mmd_tile_kernel(const float* __restrict__ X,
                                                          const float* __restrict__ Y,
                                                          const float* __restrict__ norms,
                                                          double* __restrict__ partials,
                                                          int n, int m, int T) {
    __shared__ float sA[TD][BT];
    __shared__ float sB[TD][BT];
    __shared__ float sred[4];

    const int t = blockIdx.x;
    // decode upper-triangular (bi, bj) with bi <= bj from linear index t
    // S(bi) = bi*T - bi*(bi-1)/2 is the first linear index of row bi
    double bguess = (2.0 * T + 1.0 -
                     sqrt((2.0 * T + 1.0) * (2.0 * T + 1.0) - 8.0 * (double)t)) * 0.5;
    int bi = (int)bguess;
    if (bi < 0) bi = 0;
    if (bi > T - 1) bi = T - 1;
    while ((bi + 1) * T - ((bi + 1) * bi) / 2 <= t) ++bi;   // S(bi+1) <= t : too small
    while (bi * T - (bi * (bi - 1)) / 2 > t) --bi;          // S(bi)  > t  : too big
    const int bj = bi + (t - (bi * T - (bi * (bi - 1)) / 2));

    const int tid = threadIdx.x;

    // ---- stage both 64x128 row-panels into LDS, transposed to k-major ----
    {
        const int row = tid & 63;   // lane-contiguous rows -> 2-way LDS write alias
        const int qb  = tid >> 6;   // wave id = quad base
        const int ra = bi * BT + row;
        const int rb = bj * BT + row;
        const float* Arow = (ra < n) ? (X + (size_t)ra * TD) : (Y + (size_t)(ra - n) * TD);
        const float* Brow = (rb < n) ? (X + (size_t)rb * TD) : (Y + (size_t)(rb - n) * TD);
#pragma unroll
        for (int i = 0; i < 8; ++i) {
            const int q = qb + 4 * i;           // float4 index 0..31
            float4 va = *reinterpret_cast<const float4*>(Arow + 4 * q);
            sA[4 * q + 0][row] = va.x;
            sA[4 * q + 1][row] = va.y;
            sA[4 * q + 2][row] = va.z;
            sA[4 * q + 3][row] = va.w;
            float4 vb = *reinterpret_cast<const float4*>(Brow + 4 * q);
            sB[4 * q + 0][row] = vb.x;
            sB[4 * q + 1][row] = vb.y;
            sB[4 * q + 2][row] = vb.z;
            sB[4 * q + 3][row] = vb.w;
        }
    }
    __syncthreads();

    // ---- 4x4 register tile of dot products per thread ----
    const int tx = tid & 15;
    const int ty = tid >> 4;

    float acc[4][4];
#pragma unroll
    for (int i = 0; i < 4; ++i)
#pragma unroll
        for (int j = 0; j < 4; ++j) acc[i][j] = 0.f;

#pragma unroll 16
    for (int k = 0; k < TD; ++k) {
        float4 a = *reinterpret_cast<const float4*>(&sA[k][ty * 4]);
        float4 b = *reinterpret_cast<const float4*>(&sB[k][tx * 4]);
        const float av[4] = {a.x, a.y, a.z, a.w};
        const float bv[4] = {b.x, b.y, b.z, b.w};
#pragma unroll
        for (int i = 0; i < 4; ++i)
#pragma unroll
            for (int j = 0; j < 4; ++j)
                acc[i][j] = fmaf(av[i], bv[j], acc[i][j]);
    }

    // ---- epilogue: d2 -> exp -> thread-local sum ----
    float nA[4], nB[4];
#pragma unroll
    for (int i = 0; i < 4; ++i) nA[i] = norms[bi * BT + ty * 4 + i];
#pragma unroll
    for (int j = 0; j < 4; ++j) nB[j] = norms[bj * BT + tx * 4 + j];

    const float cexp = -0.005f;  // -1 / (2 * 10^2)
    float s = 0.f;
#pragma unroll
    for (int i = 0; i < 4; ++i)
#pragma unroll
        for (int j = 0; j < 4; ++j) {
            float d2 = fmaxf(nA[i] + nB[j] - 2.f * acc[i][j], 0.f);
            s += __expf(d2 * cexp);
        }

    // ---- block reduce (fp32 within block, double partial out) ----
#pragma unroll
    for (int off = 32; off > 0; off >>= 1) s += __shfl_down(s, off, 64);
    if ((tid & 63) == 0) sred[tid >> 6] = s;
    __syncthreads();
    if (tid == 0) {
        double wa = (bi * BT < n) ? (1.0 / (double)n) : (-1.0 / (double)m);
        double wb = (bj * BT < n) ? (1.0 / (double)n) : (-1.0 / (double)m);
        double w = wa * wb * ((bi == bj) ? 1.0 : 2.0);
        partials[t] = w * (double)(sred[0] + sred[1] + sred[2] + sred[3]);
    }
}

// ---------------------------------------------------------------------------
// Kernel 3: deterministic double reduction of block partials -> scalar out
// ---------------------------------------------------------------------------
__global__ __launch_bounds__(256) void reduce_kernel(const double* __restrict__ partials,
                                                     int npart,
                                                     float* __restrict__ out) {
    __shared__ double sd[256];
    double s = 0.0;
    for (int i = threadIdx.x; i < npart; i += 256) s += partials[i];
    sd[threadIdx.x] = s;
    __syncthreads();
    for (int off = 128; off > 0; off >>= 1) {
        if ((int)threadIdx.x < off) sd[threadIdx.x] += sd[threadIdx.x + off];
        __syncthreads();
    }
    if (threadIdx.x == 0) out[0] = (float)sd[0];
}

// ---------------------------------------------------------------------------
extern "C" void kernel_launch(void* const* d_in, const int* in_sizes, int n_in,
                              void* d_out, int out_size, void* d_ws, size_t ws_size,
                              hipStream_t stream) {
    const float* X = (const float*)d_in[0];
    const float* Y = (const float*)d_in[1];
    float* out = (float*)d_out;

    const int n = in_sizes[0] / TD;
    const int m = in_sizes[1] / TD;
    const int tot = n + m;
    const int T = tot / BT;                 // 256 tiles of 64 rows
    const int npart = T * (T + 1) / 2;      // 32896 triangular tile-blocks

    float* norms = (float*)d_ws;
    double* partials = (double*)((char*)d_ws + (((size_t)tot * 4 + 255) & ~(size_t)255));

    norms_kernel<<<(tot + 255) / 256, 256, 0, stream>>>(X, Y, n, tot, norms);
    mmd_tile_kernel<<<npart, 256, 0, stream>>>(X, Y, norms, partials, n, m, T);
    reduce_kernel<<<1, 256, 0, stream>>>(partials, npart, out);
}

// Round 2
// 83.883 us; speedup vs baseline: 6.8645x; 6.8645x over previous
//
#include <hip/hip_runtime.h>
#include <math.h>

#define TD 128   // feature dimension
#define BT 64    // fallback tile rows
#define TB 128   // mfma tile rows per block

typedef _Float16 half8 __attribute__((ext_vector_type(8)));
typedef _Float16 half2v __attribute__((ext_vector_type(2)));
typedef float f32x4 __attribute__((ext_vector_type(4)));

// K = exp(-d2/(2*10^2)) = 2^(C2*d2);  C2 = -1/(200*ln2)
#define C2f   (-0.0072134752044448f)
#define M2C2f (0.0144269504088896f)   /* -2*C2 */

#if __has_builtin(__builtin_amdgcn_exp2f)
#define EXP2F(x) __builtin_amdgcn_exp2f(x)
#else
#define EXP2F(x) exp2f(x)
#endif

__device__ __forceinline__ void gload16(const void* g, void* l) {
    __builtin_amdgcn_global_load_lds(
        (const __attribute__((address_space(1))) void*)g,
        (__attribute__((address_space(3))) void*)l, 16, 0, 0);
}

// ---------------------------------------------------------------------------
// Prologue: Z -> fp16 (row-major [tot][128]) + sn2[r] = C2 * ||f16(z_r)||^2
// (norms computed in fp32 FROM THE ROUNDED fp16 values -> d2 consistent with
//  the MFMA dot products; d2_ii ~ 0)
// One wave per row: 64 lanes x float2.
// ---------------------------------------------------------------------------
__global__ __launch_bounds__(256) void cvt_norms_kernel(const float* __restrict__ X,
                                                        const float* __restrict__ Y,
                                                        int n, int tot,
                                                        _Float16* __restrict__ Z16,
                                                        float* __restrict__ sn2) {
    const int wid  = (blockIdx.x * 256 + threadIdx.x) >> 6;
    const int lane = threadIdx.x & 63;
    if (wid >= tot) return;
    const float* row = (wid < n) ? (X + (size_t)wid * TD) : (Y + (size_t)(wid - n) * TD);
    float2 v = *reinterpret_cast<const float2*>(row + lane * 2);
    _Float16 hx = (_Float16)v.x;
    _Float16 hy = (_Float16)v.y;
    half2v h2 = {hx, hy};
    *reinterpret_cast<half2v*>(Z16 + (size_t)wid * TD + lane * 2) = h2;
    float fx = (float)hx, fy = (float)hy;
    float s = fmaf(fx, fx, fy * fy);
#pragma unroll
    for (int off = 32; off > 0; off >>= 1) s += __shfl_down(s, off, 64);
    if (lane == 0) sn2[wid] = C2f * s;
}

// ---------------------------------------------------------------------------
// Main: one 128x128 tile of the symmetric pair matrix per block (triangular
// grid).  4 waves, each 64x64 output via 4x4 fragments of
// mfma_f32_16x16x32_f16.  K=128 resident in LDS (one staging per block).
// LDS: [row][16B-slot], slot XOR-swizzled by (row&7):
//   staging = global_load_lds, linear dest + inverse-swizzled source;
//   frag read = ds_read_b128 at swizzled addr  -> 2-way conflicts (free).
// ---------------------------------------------------------------------------
__global__ __launch_bounds__(256) void mmd_mfma_kernel(const _Float16* __restrict__ Z16,
                                                       const float* __restrict__ sn2,
                                                       double* __restrict__ partials,
                                                       int n, int m, int T) {
    __shared__ char sAB[2 * TB * 256];   // A panel @0, B panel @32768
    __shared__ float sred[4];

    const int t = blockIdx.x;
    double bguess = (2.0 * T + 1.0 -
                     sqrt((2.0 * T + 1.0) * (2.0 * T + 1.0) - 8.0 * (double)t)) * 0.5;
    int bi = (int)bguess;
    if (bi < 0) bi = 0;
    if (bi > T - 1) bi = T - 1;
    while ((bi + 1) * T - ((bi + 1) * bi) / 2 <= t) ++bi;
    while (bi * T - (bi * (bi - 1)) / 2 > t) --bi;
    const int bj = bi + (t - (bi * T - (bi * (bi - 1)) / 2));

    const int tid = threadIdx.x;
    const int l = tid & 63;
    const int w = tid >> 6;

    // ---- stage both panels: 32 KB each, 8 chunks of 1 KB (4 rows) per wave
    {
        const _Float16* gA = Z16 + (size_t)bi * TB * TD;
        const _Float16* gB = Z16 + (size_t)bj * TB * TD;
        const int rl = l >> 4;          // row within chunk
        const int sl = l & 15;          // dest slot (linear)
#pragma unroll
        for (int c = 0; c < 8; ++c) {
            const int ci = c * 4 + w;   // chunk 0..31
            const int r  = ci * 4 + rl; // row 0..127
            const int src = sl ^ (r & 7);            // inverse-swizzled source slot
            gload16(gA + (size_t)r * TD + src * 8, sAB + ci * 1024);
            gload16(gB + (size_t)r * TD + src * 8, sAB + 32768 + ci * 1024);
        }
    }
    __syncthreads();

    // ---- 64x64 per wave: 4x4 fragments of 16x16, K=128 in 4 steps of 32
    const int wrow = (w >> 1) * 64;
    const int wcol = (w & 1) * 64;
    const int lr = l & 15;   // A-row / B-col within 16-block
    const int kq = l >> 4;   // k quarter within K-step

    f32x4 acc[4][4];
#pragma unroll
    for (int i = 0; i < 4; ++i)
#pragma unroll
        for (int j = 0; j < 4; ++j) acc[i][j] = (f32x4){0.f, 0.f, 0.f, 0.f};

    const char* pA = sAB;
    const char* pB = sAB + 32768;
    const int swz = lr & 7;   // (row&7) == (lr&7): wrow,f*16 are multiples of 8

#pragma unroll
    for (int ks = 0; ks < 4; ++ks) {
        half8 af[4], bf[4];
#pragma unroll
        for (int f = 0; f < 4; ++f) {
            const int slot = (ks * 4 + kq) ^ swz;
            af[f] = *reinterpret_cast<const half8*>(pA + (wrow + f * 16 + lr) * 256 + slot * 16);
            bf[f] = *reinterpret_cast<const half8*>(pB + (wcol + f * 16 + lr) * 256 + slot * 16);
        }
#pragma unroll
        for (int i = 0; i < 4; ++i)
#pragma unroll
            for (int j = 0; j < 4; ++j)
                acc[i][j] = __builtin_amdgcn_mfma_f32_16x16x32_f16(af[i], bf[j], acc[i][j], 0, 0, 0);
    }

    // ---- epilogue: karg = sn2_i + sn2_j + M2C2*acc (<=0), K = 2^karg
    float sni[4][4];   // [row-frag][reg]
    float snj[4];      // [col-frag]
#pragma unroll
    for (int i = 0; i < 4; ++i)
#pragma unroll
        for (int r = 0; r < 4; ++r)
            sni[i][r] = sn2[bi * TB + wrow + i * 16 + kq * 4 + r];
#pragma unroll
    for (int j = 0; j < 4; ++j)
        snj[j] = sn2[bj * TB + wcol + j * 16 + lr];

    float s = 0.f;
#pragma unroll
    for (int i = 0; i < 4; ++i)
#pragma unroll
        for (int j = 0; j < 4; ++j)
#pragma unroll
            for (int r = 0; r < 4; ++r) {
                float karg = fmaf(M2C2f, acc[i][j][r], sni[i][r] + snj[j]);
                karg = fminf(karg, 0.f);
                s += EXP2F(karg);
            }

    // ---- block reduce -> double partial
#pragma unroll
    for (int off = 32; off > 0; off >>= 1) s += __shfl_down(s, off, 64);
    if (l == 0) sred[w] = s;
    __syncthreads();
    if (tid == 0) {
        double wa = (bi * TB < n) ? (1.0 / (double)n) : (-1.0 / (double)m);
        double wb = (bj * TB < n) ? (1.0 / (double)n) : (-1.0 / (double)m);
        double wgt = wa * wb * ((bi == bj) ? 1.0 : 2.0);
        partials[t] = wgt * (double)(sred[0] + sred[1] + sred[2] + sred[3]);
    }
}

// ---------------------------------------------------------------------------
// Fallback fp32 path (round-1, proven): used only if ws_size is too small
// ---------------------------------------------------------------------------
__global__ __launch_bounds__(256) void norms_kernel(const float* __restrict__ X,
                                                    const float* __restrict__ Y,
                                                    int n, int tot,
                                                    float* __restrict__ norms) {
    int r = blockIdx.x * 256 + threadIdx.x;
    if (r >= tot) return;
    const float* row = (r < n) ? (X + (size_t)r * TD) : (Y + (size_t)(r - n) * TD);
    float s = 0.f;
#pragma unroll
    for (int k = 0; k < TD; k += 4) {
        float4 v = *reinterpret_cast<const float4*>(row + k);
        s = fmaf(v.x, v.x, s); s = fmaf(v.y, v.y, s);
        s = fmaf(v.z, v.z, s); s = fmaf(v.w, v.w, s);
    }
    norms[r] = s;
}

__global__ __launch_bounds__(256, 2) void mmd_tile_kernel(const float* __restrict__ X,
                                                          const float* __restrict__ Y,
                                                          const float* __restrict__ norms,
                                                          double* __restrict__ partials,
                                                          int n, int m, int T) {
    __shared__ float sA[TD][BT];
    __shared__ float sB[TD][BT];
    __shared__ float sred[4];

    const int t = blockIdx.x;
    double bguess = (2.0 * T + 1.0 -
                     sqrt((2.0 * T + 1.0) * (2.0 * T + 1.0) - 8.0 * (double)t)) * 0.5;
    int bi = (int)bguess;
    if (bi < 0) bi = 0;
    if (bi > T - 1) bi = T - 1;
    while ((bi + 1) * T - ((bi + 1) * bi) / 2 <= t) ++bi;
    while (bi * T - (bi * (bi - 1)) / 2 > t) --bi;
    const int bj = bi + (t - (bi * T - (bi * (bi - 1)) / 2));

    const int tid = threadIdx.x;
    {
        const int row = tid & 63;
        const int qb  = tid >> 6;
        const int ra = bi * BT + row;
        const int rb = bj * BT + row;
        const float* Arow = (ra < n) ? (X + (size_t)ra * TD) : (Y + (size_t)(ra - n) * TD);
        const float* Brow = (rb < n) ? (X + (size_t)rb * TD) : (Y + (size_t)(rb - n) * TD);
#pragma unroll
        for (int i = 0; i < 8; ++i) {
            const int q = qb + 4 * i;
            float4 va = *reinterpret_cast<const float4*>(Arow + 4 * q);
            sA[4 * q + 0][row] = va.x; sA[4 * q + 1][row] = va.y;
            sA[4 * q + 2][row] = va.z; sA[4 * q + 3][row] = va.w;
            float4 vb = *reinterpret_cast<const float4*>(Brow + 4 * q);
            sB[4 * q + 0][row] = vb.x; sB[4 * q + 1][row] = vb.y;
            sB[4 * q + 2][row] = vb.z; sB[4 * q + 3][row] = vb.w;
        }
    }
    __syncthreads();

    const int tx = tid & 15;
    const int ty = tid >> 4;
    float acc[4][4];
#pragma unroll
    for (int i = 0; i < 4; ++i)
#pragma unroll
        for (int j = 0; j < 4; ++j) acc[i][j] = 0.f;

#pragma unroll 16
    for (int k = 0; k < TD; ++k) {
        float4 a = *reinterpret_cast<const float4*>(&sA[k][ty * 4]);
        float4 b = *reinterpret_cast<const float4*>(&sB[k][tx * 4]);
        const float av[4] = {a.x, a.y, a.z, a.w};
        const float bv[4] = {b.x, b.y, b.z, b.w};
#pragma unroll
        for (int i = 0; i < 4; ++i)
#pragma unroll
            for (int j = 0; j < 4; ++j)
                acc[i][j] = fmaf(av[i], bv[j], acc[i][j]);
    }

    float nA[4], nB[4];
#pragma unroll
    for (int i = 0; i < 4; ++i) nA[i] = norms[bi * BT + ty * 4 + i];
#pragma unroll
    for (int j = 0; j < 4; ++j) nB[j] = norms[bj * BT + tx * 4 + j];

    const float cexp = -0.005f;
    float s = 0.f;
#pragma unroll
    for (int i = 0; i < 4; ++i)
#pragma unroll
        for (int j = 0; j < 4; ++j) {
            float d2 = fmaxf(nA[i] + nB[j] - 2.f * acc[i][j], 0.f);
            s += __expf(d2 * cexp);
        }

#pragma unroll
    for (int off = 32; off > 0; off >>= 1) s += __shfl_down(s, off, 64);
    if ((tid & 63) == 0) sred[tid >> 6] = s;
    __syncthreads();
    if (tid == 0) {
        double wa = (bi * BT < n) ? (1.0 / (double)n) : (-1.0 / (double)m);
        double wb = (bj * BT < n) ? (1.0 / (double)n) : (-1.0 / (double)m);
        double wgt = wa * wb * ((bi == bj) ? 1.0 : 2.0);
        partials[t] = wgt * (double)(sred[0] + sred[1] + sred[2] + sred[3]);
    }
}

// ---------------------------------------------------------------------------
__global__ __launch_bounds__(256) void reduce_kernel(const double* __restrict__ partials,
                                                     int npart,
                                                     float* __restrict__ out) {
    __shared__ double sd[256];
    double s = 0.0;
    for (int i = threadIdx.x; i < npart; i += 256) s += partials[i];
    sd[threadIdx.x] = s;
    __syncthreads();
    for (int off = 128; off > 0; off >>= 1) {
        if ((int)threadIdx.x < off) sd[threadIdx.x] += sd[threadIdx.x + off];
        __syncthreads();
    }
    if (threadIdx.x == 0) out[0] = (float)sd[0];
}

// ---------------------------------------------------------------------------
extern "C" void kernel_launch(void* const* d_in, const int* in_sizes, int n_in,
                              void* d_out, int out_size, void* d_ws, size_t ws_size,
                              hipStream_t stream) {
    const float* X = (const float*)d_in[0];
    const float* Y = (const float*)d_in[1];
    float* out = (float*)d_out;

    const int n = in_sizes[0] / TD;
    const int m = in_sizes[1] / TD;
    const int tot = n + m;

    // fp16-MFMA path workspace: Z16 + sn2 + partials
    const size_t z16_bytes = (size_t)tot * TD * 2;
    const size_t sn2_off   = (z16_bytes + 255) & ~(size_t)255;
    const size_t sn2_bytes = (size_t)tot * 4;
    const size_t part_off  = ((sn2_off + sn2_bytes) + 255) & ~(size_t)255;
    const int Tm = tot / TB;
    const int npart_m = Tm * (Tm + 1) / 2;
    const size_t needed = part_off + (size_t)npart_m * 8;

    if (ws_size >= needed && (tot % TB) == 0 && (n % TB) == 0) {
        _Float16* Z16 = (_Float16*)d_ws;
        float* sn2 = (float*)((char*)d_ws + sn2_off);
        double* partials = (double*)((char*)d_ws + part_off);
        cvt_norms_kernel<<<(tot + 3) / 4, 256, 0, stream>>>(X, Y, n, tot, Z16, sn2);
        mmd_mfma_kernel<<<npart_m, 256, 0, stream>>>(Z16, sn2, partials, n, m, Tm);
        reduce_kernel<<<1, 256, 0, stream>>>(partials, npart_m, out);
    } else {
        const int T = tot / BT;
        const int npart = T * (T + 1) / 2;
        float* norms = (float*)d_ws;
        double* partials = (double*)((char*)d_ws + (((size_t)tot * 4 + 255) & ~(size_t)255));
        norms_kernel<<<(tot + 255) / 256, 256, 0, stream>>>(X, Y, n, tot, norms);
        mmd_tile_kernel<<<T * (T + 1) / 2, 256, 0, stream>>>(X, Y, norms, partials, n, m, T);
        reduce_kernel<<<1, 256, 0, stream>>>(partials, npart, out);
    }
}

// Round 3
// 79.475 us; speedup vs baseline: 7.2453x; 1.0555x over previous
//
#include <hip/hip_runtime.h>
#include <math.h>

#define TD 128   // feature dimension
#define BT 64    // fallback tile rows
#define TB 128   // mfma tile rows per block

typedef _Float16 half8 __attribute__((ext_vector_type(8)));
typedef _Float16 half2v __attribute__((ext_vector_type(2)));
typedef float f32x4 __attribute__((ext_vector_type(4)));

// K = exp(-d2/(2*10^2)) = 2^(C2*d2);  C2 = -1/(200*ln2)
#define C2f   (-0.0072134752044448f)
#define M2C2f (0.0144269504088896f)   /* -2*C2 */

#if __has_builtin(__builtin_amdgcn_exp2f)
#define EXP2F(x) __builtin_amdgcn_exp2f(x)
#else
#define EXP2F(x) exp2f(x)
#endif

__device__ __forceinline__ void gload16(const void* g, void* l) {
    __builtin_amdgcn_global_load_lds(
        (const __attribute__((address_space(1))) void*)g,
        (__attribute__((address_space(3))) void*)l, 16, 0, 0);
}

// ---------------------------------------------------------------------------
// Prologue: Z -> fp16 (row-major [tot][128]) + En[r] = exp2(C2*||f16(z_r)||^2)
// (norms computed in fp32 FROM THE ROUNDED fp16 values -> d2 consistent with
//  the MFMA dot products; d2_ii ~ 0)
// One wave per row: 64 lanes x float2.
// ---------------------------------------------------------------------------
__global__ __launch_bounds__(256) void cvt_norms_kernel(const float* __restrict__ X,
                                                        const float* __restrict__ Y,
                                                        int n, int tot,
                                                        _Float16* __restrict__ Z16,
                                                        float* __restrict__ En) {
    const int wid  = (blockIdx.x * 256 + threadIdx.x) >> 6;
    const int lane = threadIdx.x & 63;
    if (wid >= tot) return;
    const float* row = (wid < n) ? (X + (size_t)wid * TD) : (Y + (size_t)(wid - n) * TD);
    float2 v = *reinterpret_cast<const float2*>(row + lane * 2);
    _Float16 hx = (_Float16)v.x;
    _Float16 hy = (_Float16)v.y;
    half2v h2 = {hx, hy};
    *reinterpret_cast<half2v*>(Z16 + (size_t)wid * TD + lane * 2) = h2;
    float fx = (float)hx, fy = (float)hy;
    float s = fmaf(fx, fx, fy * fy);
#pragma unroll
    for (int off = 32; off > 0; off >>= 1) s += __shfl_down(s, off, 64);
    if (lane == 0) En[wid] = EXP2F(C2f * s);
}

// ---------------------------------------------------------------------------
// Main: one 128x128 tile of the symmetric pair matrix per block (triangular
// grid).  4 waves, each 64x64 output via 4x4 fragments of
// mfma_f32_16x16x32_f16.  K=128 resident in LDS (one staging per block).
// LDS: [row][16B-slot], slot XOR-swizzled by (row&7).
// Epilogue: K_ij = Ei * Ej * exp2(M2C2 * dot)  (exp2 factorization --
// removes per-pair norm-add and clamp; 8 independent fma chains).
// ---------------------------------------------------------------------------
__global__ __launch_bounds__(256) void mmd_mfma_kernel(const _Float16* __restrict__ Z16,
                                                       const float* __restrict__ En,
                                                       double* __restrict__ partials,
                                                       int n, int m, int T) {
    __shared__ char sAB[2 * TB * 256];   // A panel @0, B panel @32768
    __shared__ float sred[4];

    const int t = blockIdx.x;
    double bguess = (2.0 * T + 1.0 -
                     sqrt((2.0 * T + 1.0) * (2.0 * T + 1.0) - 8.0 * (double)t)) * 0.5;
    int bi = (int)bguess;
    if (bi < 0) bi = 0;
    if (bi > T - 1) bi = T - 1;
    while ((bi + 1) * T - ((bi + 1) * bi) / 2 <= t) ++bi;
    while (bi * T - (bi * (bi - 1)) / 2 > t) --bi;
    const int bj = bi + (t - (bi * T - (bi * (bi - 1)) / 2));

    const int tid = threadIdx.x;
    const int l = tid & 63;
    const int w = tid >> 6;

    // ---- stage both panels: 32 KB each, 8 chunks of 1 KB (4 rows) per wave
    {
        const _Float16* gA = Z16 + (size_t)bi * TB * TD;
        const _Float16* gB = Z16 + (size_t)bj * TB * TD;
        const int rl = l >> 4;          // row within chunk
        const int sl = l & 15;          // dest slot (linear)
#pragma unroll
        for (int c = 0; c < 8; ++c) {
            const int ci = c * 4 + w;   // chunk 0..31
            const int r  = ci * 4 + rl; // row 0..127
            const int src = sl ^ (r & 7);            // inverse-swizzled source slot
            gload16(gA + (size_t)r * TD + src * 8, sAB + ci * 1024);
            gload16(gB + (size_t)r * TD + src * 8, sAB + 32768 + ci * 1024);
        }
    }
    __syncthreads();

    // ---- 64x64 per wave: 4x4 fragments of 16x16, K=128 in 4 steps of 32
    const int wrow = (w >> 1) * 64;
    const int wcol = (w & 1) * 64;
    const int lr = l & 15;   // A-row / B-col within 16-block
    const int kq = l >> 4;   // k quarter within K-step

    f32x4 acc[4][4];
#pragma unroll
    for (int i = 0; i < 4; ++i)
#pragma unroll
        for (int j = 0; j < 4; ++j) acc[i][j] = (f32x4){0.f, 0.f, 0.f, 0.f};

    const char* pA = sAB;
    const char* pB = sAB + 32768;
    const int swz = lr & 7;   // (row&7) == (lr&7): wrow,f*16 are multiples of 8

#pragma unroll
    for (int ks = 0; ks < 4; ++ks) {
        half8 af[4], bf[4];
#pragma unroll
        for (int f = 0; f < 4; ++f) {
            const int slot = (ks * 4 + kq) ^ swz;
            af[f] = *reinterpret_cast<const half8*>(pA + (wrow + f * 16 + lr) * 256 + slot * 16);
            bf[f] = *reinterpret_cast<const half8*>(pB + (wcol + f * 16 + lr) * 256 + slot * 16);
        }
#pragma unroll
        for (int i = 0; i < 4; ++i)
#pragma unroll
            for (int j = 0; j < 4; ++j)
                acc[i][j] = __builtin_amdgcn_mfma_f32_16x16x32_f16(af[i], bf[j], acc[i][j], 0, 0, 0);
    }

    // ---- epilogue: K = Ei * Ej * exp2(M2C2 * dot); per pair: mul+exp+fma
    float Ei[4][4];   // [row-frag][reg]
    float Ej[4];      // [col-frag]
#pragma unroll
    for (int i = 0; i < 4; ++i)
#pragma unroll
        for (int r = 0; r < 4; ++r)
            Ei[i][r] = En[bi * TB + wrow + i * 16 + kq * 4 + r];
#pragma unroll
    for (int j = 0; j < 4; ++j)
        Ej[j] = En[bj * TB + wcol + j * 16 + lr];

    float s = 0.f;
#pragma unroll
    for (int j = 0; j < 4; ++j) {
        float sj0 = 0.f, sj1 = 0.f;   // 2 independent chains per j
#pragma unroll
        for (int i = 0; i < 4; ++i) {
#pragma unroll
            for (int r = 0; r < 4; ++r) {
                float e = EXP2F(M2C2f * acc[i][j][r]);
                if (r & 1) sj1 = fmaf(Ei[i][r], e, sj1);
                else       sj0 = fmaf(Ei[i][r], e, sj0);
            }
        }
        s = fmaf(Ej[j], sj0 + sj1, s);
    }

    // ---- block reduce -> double partial
#pragma unroll
    for (int off = 32; off > 0; off >>= 1) s += __shfl_down(s, off, 64);
    if (l == 0) sred[w] = s;
    __syncthreads();
    if (tid == 0) {
        double wa = (bi * TB < n) ? (1.0 / (double)n) : (-1.0 / (double)m);
        double wb = (bj * TB < n) ? (1.0 / (double)n) : (-1.0 / (double)m);
        double wgt = wa * wb * ((bi == bj) ? 1.0 : 2.0);
        partials[t] = wgt * (double)(sred[0] + sred[1] + sred[2] + sred[3]);
    }
}

// ---------------------------------------------------------------------------
// Fallback fp32 path (round-1, proven): used only if ws_size is too small
// ---------------------------------------------------------------------------
__global__ __launch_bounds__(256) void norms_kernel(const float* __restrict__ X,
                                                    const float* __restrict__ Y,
                                                    int n, int tot,
                                                    float* __restrict__ norms) {
    int r = blockIdx.x * 256 + threadIdx.x;
    if (r >= tot) return;
    const float* row = (r < n) ? (X + (size_t)r * TD) : (Y + (size_t)(r - n) * TD);
    float s = 0.f;
#pragma unroll
    for (int k = 0; k < TD; k += 4) {
        float4 v = *reinterpret_cast<const float4*>(row + k);
        s = fmaf(v.x, v.x, s); s = fmaf(v.y, v.y, s);
        s = fmaf(v.z, v.z, s); s = fmaf(v.w, v.w, s);
    }
    norms[r] = s;
}

__global__ __launch_bounds__(256, 2) void mmd_tile_kernel(const float* __restrict__ X,
                                                          const float* __restrict__ Y,
                                                          const float* __restrict__ norms,
                                                          double* __restrict__ partials,
                                                          int n, int m, int T) {
    __shared__ float sA[TD][BT];
    __shared__ float sB[TD][BT];
    __shared__ float sred[4];

    const int t = blockIdx.x;
    double bguess = (2.0 * T + 1.0 -
                     sqrt((2.0 * T + 1.0) * (2.0 * T + 1.0) - 8.0 * (double)t)) * 0.5;
    int bi = (int)bguess;
    if (bi < 0) bi = 0;
    if (bi > T - 1) bi = T - 1;
    while ((bi + 1) * T - ((bi + 1) * bi) / 2 <= t) ++bi;
    while (bi * T - (bi * (bi - 1)) / 2 > t) --bi;
    const int bj = bi + (t - (bi * T - (bi * (bi - 1)) / 2));

    const int tid = threadIdx.x;
    {
        const int row = tid & 63;
        const int qb  = tid >> 6;
        const int ra = bi * BT + row;
        const int rb = bj * BT + row;
        const float* Arow = (ra < n) ? (X + (size_t)ra * TD) : (Y + (size_t)(ra - n) * TD);
        const float* Brow = (rb < n) ? (X + (size_t)rb * TD) : (Y + (size_t)(rb - n) * TD);
#pragma unroll
        for (int i = 0; i < 8; ++i) {
            const int q = qb + 4 * i;
            float4 va = *reinterpret_cast<const float4*>(Arow + 4 * q);
            sA[4 * q + 0][row] = va.x; sA[4 * q + 1][row] = va.y;
            sA[4 * q + 2][row] = va.z; sA[4 * q + 3][row] = va.w;
            float4 vb = *reinterpret_cast<const float4*>(Brow + 4 * q);
            sB[4 * q + 0][row] = vb.x; sB[4 * q + 1][row] = vb.y;
            sB[4 * q + 2][row] = vb.z; sB[4 * q + 3][row] = vb.w;
        }
    }
    __syncthreads();

    const int tx = tid & 15;
    const int ty = tid >> 4;
    float acc[4][4];
#pragma unroll
    for (int i = 0; i < 4; ++i)
#pragma unroll
        for (int j = 0; j < 4; ++j) acc[i][j] = 0.f;

#pragma unroll 16
    for (int k = 0; k < TD; ++k) {
        float4 a = *reinterpret_cast<const float4*>(&sA[k][ty * 4]);
        float4 b = *reinterpret_cast<const float4*>(&sB[k][tx * 4]);
        const float av[4] = {a.x, a.y, a.z, a.w};
        const float bv[4] = {b.x, b.y, b.z, b.w};
#pragma unroll
        for (int i = 0; i < 4; ++i)
#pragma unroll
            for (int j = 0; j < 4; ++j)
                acc[i][j] = fmaf(av[i], bv[j], acc[i][j]);
    }

    float nA[4], nB[4];
#pragma unroll
    for (int i = 0; i < 4; ++i) nA[i] = norms[bi * BT + ty * 4 + i];
#pragma unroll
    for (int j = 0; j < 4; ++j) nB[j] = norms[bj * BT + tx * 4 + j];

    const float cexp = -0.005f;
    float s = 0.f;
#pragma unroll
    for (int i = 0; i < 4; ++i)
#pragma unroll
        for (int j = 0; j < 4; ++j) {
            float d2 = fmaxf(nA[i] + nB[j] - 2.f * acc[i][j], 0.f);
            s += __expf(d2 * cexp);
        }

#pragma unroll
    for (int off = 32; off > 0; off >>= 1) s += __shfl_down(s, off, 64);
    if ((tid & 63) == 0) sred[tid >> 6] = s;
    __syncthreads();
    if (tid == 0) {
        double wa = (bi * BT < n) ? (1.0 / (double)n) : (-1.0 / (double)m);
        double wb = (bj * BT < n) ? (1.0 / (double)n) : (-1.0 / (double)m);
        double wgt = wa * wb * ((bi == bj) ? 1.0 : 2.0);
        partials[t] = wgt * (double)(sred[0] + sred[1] + sred[2] + sred[3]);
    }
}

// ---------------------------------------------------------------------------
__global__ __launch_bounds__(256) void reduce_kernel(const double* __restrict__ partials,
                                                     int npart,
                                                     float* __restrict__ out) {
    __shared__ double sd[256];
    double s = 0.0;
    for (int i = threadIdx.x; i < npart; i += 256) s += partials[i];
    sd[threadIdx.x] = s;
    __syncthreads();
    for (int off = 128; off > 0; off >>= 1) {
        if ((int)threadIdx.x < off) sd[threadIdx.x] += sd[threadIdx.x + off];
        __syncthreads();
    }
    if (threadIdx.x == 0) out[0] = (float)sd[0];
}

// ---------------------------------------------------------------------------
extern "C" void kernel_launch(void* const* d_in, const int* in_sizes, int n_in,
                              void* d_out, int out_size, void* d_ws, size_t ws_size,
                              hipStream_t stream) {
    const float* X = (const float*)d_in[0];
    const float* Y = (const float*)d_in[1];
    float* out = (float*)d_out;

    const int n = in_sizes[0] / TD;
    const int m = in_sizes[1] / TD;
    const int tot = n + m;

    // fp16-MFMA path workspace: Z16 + En + partials
    const size_t z16_bytes = (size_t)tot * TD * 2;
    const size_t sn2_off   = (z16_bytes + 255) & ~(size_t)255;
    const size_t sn2_bytes = (size_t)tot * 4;
    const size_t part_off  = ((sn2_off + sn2_bytes) + 255) & ~(size_t)255;
    const int Tm = tot / TB;
    const int npart_m = Tm * (Tm + 1) / 2;
    const size_t needed = part_off + (size_t)npart_m * 8;

    if (ws_size >= needed && (tot % TB) == 0 && (n % TB) == 0) {
        _Float16* Z16 = (_Float16*)d_ws;
        float* En = (float*)((char*)d_ws + sn2_off);
        double* partials = (double*)((char*)d_ws + part_off);
        cvt_norms_kernel<<<(tot + 3) / 4, 256, 0, stream>>>(X, Y, n, tot, Z16, En);
        mmd_mfma_kernel<<<npart_m, 256, 0, stream>>>(Z16, En, partials, n, m, Tm);
        reduce_kernel<<<1, 256, 0, stream>>>(partials, npart_m, out);
    } else {
        const int T = tot / BT;
        const int npart = T * (T + 1) / 2;
        float* norms = (float*)d_ws;
        double* partials = (double*)((char*)d_ws + (((size_t)tot * 4 + 255) & ~(size_t)255));
        norms_kernel<<<(tot + 255) / 256, 256, 0, stream>>>(X, Y, n, tot, norms);
        mmd_tile_kernel<<<T * (T + 1) / 2, 256, 0, stream>>>(X, Y, norms, partials, n, m, T);
        reduce_kernel<<<1, 256, 0, stream>>>(partials, npart, out);
    }
}

// Round 4
// 68.904 us; speedup vs baseline: 8.3568x; 1.1534x over previous
//
#include <hip/hip_runtime.h>
#include <math.h>

#define TD 128   // feature dimension
#define BT 64    // fallback tile rows
#define TB 256   // mfma tile rows per block (256x256 tiles)

typedef _Float16 half8 __attribute__((ext_vector_type(8)));
typedef _Float16 half2v __attribute__((ext_vector_type(2)));
typedef float f32x4 __attribute__((ext_vector_type(4)));

// K = exp(-d2/(2*10^2)) = 2^(C2*d2);  C2 = -1/(200*ln2)
#define C2f   (-0.0072134752044448f)
#define M2C2f (0.0144269504088896f)   /* -2*C2 */

#if __has_builtin(__builtin_amdgcn_exp2f)
#define EXP2F(x) __builtin_amdgcn_exp2f(x)
#else
#define EXP2F(x) exp2f(x)
#endif

__device__ __forceinline__ void gload16(const void* g, void* l) {
    __builtin_amdgcn_global_load_lds(
        (const __attribute__((address_space(1))) void*)g,
        (__attribute__((address_space(3))) void*)l, 16, 0, 0);
}

// LDS layout (bytes): A panel [256 rows][256B] @0, B panel @65536,
// EnA slice (256 f32) @131072, EnB slice @132096, sred @133120
#define LDS_B   65536
#define LDS_EA  131072
#define LDS_EB  132096
#define LDS_RED 133120

// ---------------------------------------------------------------------------
// Prologue: Z -> fp16 (row-major [tot][128]) + En[r] = exp2(C2*||f16(z_r)||^2)
// (norms computed in fp32 FROM THE ROUNDED fp16 values -> d2 consistent with
//  the MFMA dot products; d2_ii ~ 0)
// ---------------------------------------------------------------------------
__global__ __launch_bounds__(256) void cvt_norms_kernel(const float* __restrict__ X,
                                                        const float* __restrict__ Y,
                                                        int n, int tot,
                                                        _Float16* __restrict__ Z16,
                                                        float* __restrict__ En) {
    const int wid  = (blockIdx.x * 256 + threadIdx.x) >> 6;
    const int lane = threadIdx.x & 63;
    if (wid >= tot) return;
    const float* row = (wid < n) ? (X + (size_t)wid * TD) : (Y + (size_t)(wid - n) * TD);
    float2 v = *reinterpret_cast<const float2*>(row + lane * 2);
    _Float16 hx = (_Float16)v.x;
    _Float16 hy = (_Float16)v.y;
    half2v h2 = {hx, hy};
    *reinterpret_cast<half2v*>(Z16 + (size_t)wid * TD + lane * 2) = h2;
    float fx = (float)hx, fy = (float)hy;
    float s = fmaf(fx, fx, fy * fy);
#pragma unroll
    for (int off = 32; off > 0; off >>= 1) s += __shfl_down(s, off, 64);
    if (lane == 0) En[wid] = EXP2F(C2f * s);
}

// ---------------------------------------------------------------------------
// Main: one 256x256 tile per block (triangular grid), 512 threads / 8 waves.
// Wave grid 2x4: each wave owns 128 rows x 64 cols = 8x4 fragments of
// mfma_f32_16x16x32_f16, K=128 resident in LDS (one staging per block).
// LDS rows are 256B; 16B slot index XOR-swizzled by (row&15) so a
// fragment-read wave-inst touches 16 distinct slots per 16-lane group.
// Epilogue: K_ij = Ei * Ej * exp2(M2C2*dot), En slices read from LDS.
// ---------------------------------------------------------------------------
__global__ __launch_bounds__(512, 2) void mmd_mfma_kernel(const _Float16* __restrict__ Z16,
                                                          const float* __restrict__ En,
                                                          double* __restrict__ partials,
                                                          int n, int m, int T) {
    __shared__ char sAB[133152];

    const int t = blockIdx.x;
    double bguess = (2.0 * T + 1.0 -
                     sqrt((2.0 * T + 1.0) * (2.0 * T + 1.0) - 8.0 * (double)t)) * 0.5;
    int bi = (int)bguess;
    if (bi < 0) bi = 0;
    if (bi > T - 1) bi = T - 1;
    while ((bi + 1) * T - ((bi + 1) * bi) / 2 <= t) ++bi;
    while (bi * T - (bi * (bi - 1)) / 2 > t) --bi;
    const int bj = bi + (t - (bi * T - (bi * (bi - 1)) / 2));

    const int tid = threadIdx.x;
    const int l = tid & 63;
    const int w = tid >> 6;           // wave 0..7

    // ---- stage both 256-row panels (64KB each) + En slices (1KB each) ----
    {
        const _Float16* gA = Z16 + (size_t)bi * TB * TD;
        const _Float16* gB = Z16 + (size_t)bj * TB * TD;
        const int rl = l >> 4;          // row within 4-row chunk
        const int sl = l & 15;          // dest slot (linear)
#pragma unroll
        for (int c = 0; c < 8; ++c) {
            const int ci = c * 8 + w;   // chunk 0..63 (1KB, 4 rows)
            const int r  = ci * 4 + rl; // row 0..255
            const int src = sl ^ (r & 15);           // inverse-swizzled source slot
            gload16(gA + (size_t)r * TD + src * 8, sAB + ci * 1024);
            gload16(gB + (size_t)r * TD + src * 8, sAB + LDS_B + ci * 1024);
        }
        if (w == 0) gload16(En + bi * TB + l * 4, sAB + LDS_EA);
        if (w == 1) gload16(En + bj * TB + l * 4, sAB + LDS_EB);
    }
    __syncthreads();

    // ---- 128x64 per wave: 8x4 fragments of 16x16, K=128 in 4 steps of 32
    const int wrow = (w >> 2) * 128;   // 0 or 128
    const int wcol = (w & 3) * 64;     // 0,64,128,192
    const int lr = l & 15;   // A-row / B-col within 16-block
    const int kq = l >> 4;   // k quarter within K-step

    const char* pA = sAB;
    const char* pB = sAB + LDS_B;

    f32x4 acc[8][4];
    const f32x4 zero4 = {0.f, 0.f, 0.f, 0.f};

    // ks = 0 peeled: MFMA with zero C (kills 128 per-thread init movs)
    {
        half8 bf[4];
#pragma unroll
        for (int j = 0; j < 4; ++j) {
            const int slot = kq ^ lr;
            bf[j] = *reinterpret_cast<const half8*>(pB + (wcol + j * 16 + lr) * 256 + slot * 16);
        }
#pragma unroll
        for (int i = 0; i < 8; ++i) {
            const int slot = kq ^ lr;
            half8 af = *reinterpret_cast<const half8*>(pA + (wrow + i * 16 + lr) * 256 + slot * 16);
#pragma unroll
            for (int j = 0; j < 4; ++j)
                acc[i][j] = __builtin_amdgcn_mfma_f32_16x16x32_f16(af, bf[j], zero4, 0, 0, 0);
        }
    }
#pragma unroll
    for (int ks = 1; ks < 4; ++ks) {
        half8 bf[4];
        const int slot = (ks * 4 + kq) ^ lr;
#pragma unroll
        for (int j = 0; j < 4; ++j)
            bf[j] = *reinterpret_cast<const half8*>(pB + (wcol + j * 16 + lr) * 256 + slot * 16);
#pragma unroll
        for (int i = 0; i < 8; ++i) {
            half8 af = *reinterpret_cast<const half8*>(pA + (wrow + i * 16 + lr) * 256 + slot * 16);
#pragma unroll
            for (int j = 0; j < 4; ++j)
                acc[i][j] = __builtin_amdgcn_mfma_f32_16x16x32_f16(af, bf[j], acc[i][j], 0, 0, 0);
        }
    }

    // ---- epilogue: K = Ei * Ej * exp2(M2C2 * dot); En slices from LDS ----
    float Ej[4];
#pragma unroll
    for (int j = 0; j < 4; ++j)
        Ej[j] = *reinterpret_cast<const float*>(sAB + LDS_EB + (wcol + j * 16 + lr) * 4);
    f32x4 EiV[8];
#pragma unroll
    for (int i = 0; i < 8; ++i)
        EiV[i] = *reinterpret_cast<const f32x4*>(sAB + LDS_EA + (wrow + i * 16 + kq * 4) * 4);

    float s = 0.f;
#pragma unroll
    for (int j = 0; j < 4; ++j) {
        float sj0 = 0.f, sj1 = 0.f;   // 2 independent chains per j
#pragma unroll
        for (int i = 0; i < 8; ++i) {
#pragma unroll
            for (int r = 0; r < 4; ++r) {
                float e = EXP2F(M2C2f * acc[i][j][r]);
                if (r & 1) sj1 = fmaf(EiV[i][r], e, sj1);
                else       sj0 = fmaf(EiV[i][r], e, sj0);
            }
        }
        s = fmaf(Ej[j], sj0 + sj1, s);
    }

    // ---- block reduce -> double partial
#pragma unroll
    for (int off = 32; off > 0; off >>= 1) s += __shfl_down(s, off, 64);
    float* sred = reinterpret_cast<float*>(sAB + LDS_RED);
    if (l == 0) sred[w] = s;
    __syncthreads();
    if (tid == 0) {
        float bs = 0.f;
#pragma unroll
        for (int q = 0; q < 8; ++q) bs += sred[q];
        double wa = (bi * TB < n) ? (1.0 / (double)n) : (-1.0 / (double)m);
        double wb = (bj * TB < n) ? (1.0 / (double)n) : (-1.0 / (double)m);
        double wgt = wa * wb * ((bi == bj) ? 1.0 : 2.0);
        partials[t] = wgt * (double)bs;
    }
}

// ---------------------------------------------------------------------------
// Fallback fp32 path (round-1, proven): used only if ws/shape unsuitable
// ---------------------------------------------------------------------------
__global__ __launch_bounds__(256) void norms_kernel(const float* __restrict__ X,
                                                    const float* __restrict__ Y,
                                                    int n, int tot,
                                                    float* __restrict__ norms) {
    int r = blockIdx.x * 256 + threadIdx.x;
    if (r >= tot) return;
    const float* row = (r < n) ? (X + (size_t)r * TD) : (Y + (size_t)(r - n) * TD);
    float s = 0.f;
#pragma unroll
    for (int k = 0; k < TD; k += 4) {
        float4 v = *reinterpret_cast<const float4*>(row + k);
        s = fmaf(v.x, v.x, s); s = fmaf(v.y, v.y, s);
        s = fmaf(v.z, v.z, s); s = fmaf(v.w, v.w, s);
    }
    norms[r] = s;
}

__global__ __launch_bounds__(256, 2) void mmd_tile_kernel(const float* __restrict__ X,
                                                          const float* __restrict__ Y,
                                                          const float* __restrict__ norms,
                                                          double* __restrict__ partials,
                                                          int n, int m, int T) {
    __shared__ float sA[TD][BT];
    __shared__ float sB[TD][BT];
    __shared__ float sredf[4];

    const int t = blockIdx.x;
    double bguess = (2.0 * T + 1.0 -
                     sqrt((2.0 * T + 1.0) * (2.0 * T + 1.0) - 8.0 * (double)t)) * 0.5;
    int bi = (int)bguess;
    if (bi < 0) bi = 0;
    if (bi > T - 1) bi = T - 1;
    while ((bi + 1) * T - ((bi + 1) * bi) / 2 <= t) ++bi;
    while (bi * T - (bi * (bi - 1)) / 2 > t) --bi;
    const int bj = bi + (t - (bi * T - (bi * (bi - 1)) / 2));

    const int tid = threadIdx.x;
    {
        const int row = tid & 63;
        const int qb  = tid >> 6;
        const int ra = bi * BT + row;
        const int rb = bj * BT + row;
        const float* Arow = (ra < n) ? (X + (size_t)ra * TD) : (Y + (size_t)(ra - n) * TD);
        const float* Brow = (rb < n) ? (X + (size_t)rb * TD) : (Y + (size_t)(rb - n) * TD);
#pragma unroll
        for (int i = 0; i < 8; ++i) {
            const int q = qb + 4 * i;
            float4 va = *reinterpret_cast<const float4*>(Arow + 4 * q);
            sA[4 * q + 0][row] = va.x; sA[4 * q + 1][row] = va.y;
            sA[4 * q + 2][row] = va.z; sA[4 * q + 3][row] = va.w;
            float4 vb = *reinterpret_cast<const float4*>(Brow + 4 * q);
            sB[4 * q + 0][row] = vb.x; sB[4 * q + 1][row] = vb.y;
            sB[4 * q + 2][row] = vb.z; sB[4 * q + 3][row] = vb.w;
        }
    }
    __syncthreads();

    const int tx = tid & 15;
    const int ty = tid >> 4;
    float acc[4][4];
#pragma unroll
    for (int i = 0; i < 4; ++i)
#pragma unroll
        for (int j = 0; j < 4; ++j) acc[i][j] = 0.f;

#pragma unroll 16
    for (int k = 0; k < TD; ++k) {
        float4 a = *reinterpret_cast<const float4*>(&sA[k][ty * 4]);
        float4 b = *reinterpret_cast<const float4*>(&sB[k][tx * 4]);
        const float av[4] = {a.x, a.y, a.z, a.w};
        const float bv[4] = {b.x, b.y, b.z, b.w};
#pragma unroll
        for (int i = 0; i < 4; ++i)
#pragma unroll
            for (int j = 0; j < 4; ++j)
                acc[i][j] = fmaf(av[i], bv[j], acc[i][j]);
    }

    float nA[4], nB[4];
#pragma unroll
    for (int i = 0; i < 4; ++i) nA[i] = norms[bi * BT + ty * 4 + i];
#pragma unroll
    for (int j = 0; j < 4; ++j) nB[j] = norms[bj * BT + tx * 4 + j];

    const float cexp = -0.005f;
    float s = 0.f;
#pragma unroll
    for (int i = 0; i < 4; ++i)
#pragma unroll
        for (int j = 0; j < 4; ++j) {
            float d2 = fmaxf(nA[i] + nB[j] - 2.f * acc[i][j], 0.f);
            s += __expf(d2 * cexp);
        }

#pragma unroll
    for (int off = 32; off > 0; off >>= 1) s += __shfl_down(s, off, 64);
    if ((tid & 63) == 0) sredf[tid >> 6] = s;
    __syncthreads();
    if (tid == 0) {
        double wa = (bi * BT < n) ? (1.0 / (double)n) : (-1.0 / (double)m);
        double wb = (bj * BT < n) ? (1.0 / (double)n) : (-1.0 / (double)m);
        double wgt = wa * wb * ((bi == bj) ? 1.0 : 2.0);
        partials[t] = wgt * (double)(sredf[0] + sredf[1] + sredf[2] + sredf[3]);
    }
}

// ---------------------------------------------------------------------------
__global__ __launch_bounds__(256) void reduce_kernel(const double* __restrict__ partials,
                                                     int npart,
                                                     float* __restrict__ out) {
    __shared__ double sd[256];
    double s = 0.0;
    for (int i = threadIdx.x; i < npart; i += 256) s += partials[i];
    sd[threadIdx.x] = s;
    __syncthreads();
    for (int off = 128; off > 0; off >>= 1) {
        if ((int)threadIdx.x < off) sd[threadIdx.x] += sd[threadIdx.x + off];
        __syncthreads();
    }
    if (threadIdx.x == 0) out[0] = (float)sd[0];
}

// ---------------------------------------------------------------------------
extern "C" void kernel_launch(void* const* d_in, const int* in_sizes, int n_in,
                              void* d_out, int out_size, void* d_ws, size_t ws_size,
                              hipStream_t stream) {
    const float* X = (const float*)d_in[0];
    const float* Y = (const float*)d_in[1];
    float* out = (float*)d_out;

    const int n = in_sizes[0] / TD;
    const int m = in_sizes[1] / TD;
    const int tot = n + m;

    // fp16-MFMA path workspace: Z16 + En + partials
    const size_t z16_bytes = (size_t)tot * TD * 2;
    const size_t en_off    = (z16_bytes + 255) & ~(size_t)255;
    const size_t en_bytes  = (size_t)tot * 4;
    const size_t part_off  = ((en_off + en_bytes) + 255) & ~(size_t)255;
    const int Tm = tot / TB;
    const int npart_m = Tm * (Tm + 1) / 2;
    const size_t needed = part_off + (size_t)npart_m * 8;

    if (ws_size >= needed && (tot % TB) == 0 && (n % TB) == 0) {
        _Float16* Z16 = (_Float16*)d_ws;
        float* En = (float*)((char*)d_ws + en_off);
        double* partials = (double*)((char*)d_ws + part_off);
        cvt_norms_kernel<<<(tot + 3) / 4, 256, 0, stream>>>(X, Y, n, tot, Z16, En);
        mmd_mfma_kernel<<<npart_m, 512, 0, stream>>>(Z16, En, partials, n, m, Tm);
        reduce_kernel<<<1, 256, 0, stream>>>(partials, npart_m, out);
    } else {
        const int T = tot / BT;
        const int npart = T * (T + 1) / 2;
        float* norms = (float*)d_ws;
        double* partials = (double*)((char*)d_ws + (((size_t)tot * 4 + 255) & ~(size_t)255));
        norms_kernel<<<(tot + 255) / 256, 256, 0, stream>>>(X, Y, n, tot, norms);
        mmd_tile_kernel<<<npart, 256, 0, stream>>>(X, Y, norms, partials, n, m, T);
        reduce_kernel<<<1, 256, 0, stream>>>(partials, npart, out);
    }
}

// Round 5
// 67.139 us; speedup vs baseline: 8.5764x; 1.0263x over previous
//
#include <hip/hip_runtime.h>
#include <math.h>

#define TD 128   // feature dimension
#define BT 64    // fallback tile rows
#define TB 256   // tile rows per block (256x256 tiles)
#define GRID 256 // persistent blocks, 1 per CU

typedef _Float16 half8 __attribute__((ext_vector_type(8)));
typedef _Float16 half2v __attribute__((ext_vector_type(2)));
typedef float f32x4 __attribute__((ext_vector_type(4)));

// K = exp(-d2/(2*10^2)) = 2^(C2*d2);  C2 = -1/(200*ln2)
#define C2f   (-0.0072134752044448f)
#define M2C2f (0.0144269504088896f)   /* -2*C2 */

#if __has_builtin(__builtin_amdgcn_exp2f)
#define EXP2F(x) __builtin_amdgcn_exp2f(x)
#else
#define EXP2F(x) exp2f(x)
#endif

// LDS layout (bytes): 4 half-K panels [256 rows][64 elem = 128B] + En + sred
#define LA0 0
#define LA1 32768
#define LB0 65536
#define LB1 98304
#define LEA 131072
#define LEB 132096
#define LRED 133120
#define LDS_TOT 133152

#define FENCE() asm volatile("" ::: "memory")
#define SCHEDB() __builtin_amdgcn_sched_barrier(0)

__device__ __forceinline__ void gload16(const void* g, void* l) {
    __builtin_amdgcn_global_load_lds(
        (const __attribute__((address_space(1))) void*)g,
        (__attribute__((address_space(3))) void*)l, 16, 0, 0);
}

__device__ __forceinline__ void decode_tile(int t, int T, int& bi, int& bj) {
    double bguess = (2.0 * T + 1.0 -
                     sqrt((2.0 * T + 1.0) * (2.0 * T + 1.0) - 8.0 * (double)t)) * 0.5;
    int b = (int)bguess;
    if (b < 0) b = 0;
    if (b > T - 1) b = T - 1;
    while ((b + 1) * T - ((b + 1) * b) / 2 <= t) ++b;
    while (b * T - (b * (b - 1)) / 2 > t) --b;
    bi = b;
    bj = b + (t - (b * T - (b * (b - 1)) / 2));
}

// ---------------------------------------------------------------------------
// Prologue: Z -> fp16 + En[r] = exp2(C2*||f16(z_r)||^2)
// ---------------------------------------------------------------------------
__global__ __launch_bounds__(256) void cvt_norms_kernel(const float* __restrict__ X,
                                                        const float* __restrict__ Y,
                                                        int n, int tot,
                                                        _Float16* __restrict__ Z16,
                                                        float* __restrict__ En) {
    const int wid  = (blockIdx.x * 256 + threadIdx.x) >> 6;
    const int lane = threadIdx.x & 63;
    if (wid >= tot) return;
    const float* row = (wid < n) ? (X + (size_t)wid * TD) : (Y + (size_t)(wid - n) * TD);
    float2 v = *reinterpret_cast<const float2*>(row + lane * 2);
    _Float16 hx = (_Float16)v.x;
    _Float16 hy = (_Float16)v.y;
    half2v h2 = {hx, hy};
    *reinterpret_cast<half2v*>(Z16 + (size_t)wid * TD + lane * 2) = h2;
    float fx = (float)hx, fy = (float)hy;
    float s = fmaf(fx, fx, fy * fy);
#pragma unroll
    for (int off = 32; off > 0; off >>= 1) s += __shfl_down(s, off, 64);
    if (lane == 0) En[wid] = EXP2F(C2f * s);
}

// ---------------------------------------------------------------------------
// Main: persistent blocks, grid-stride over triangular 256x256 tiles.
// K=128 split in two 64-halves, 4 LDS buffers; cross-tile software pipeline
// with raw s_barrier + counted vmcnt (prefetch stays in flight across
// barriers).  8 waves x (128x64 out via 8x4 frags of mfma 16x16x32 f16).
// ---------------------------------------------------------------------------
__global__ __launch_bounds__(512, 2) void mmd_pipe_kernel(const _Float16* __restrict__ Z16,
                                                          const float* __restrict__ En,
                                                          double* __restrict__ partials,
                                                          int n, int m, int T, int ntiles) {
    __shared__ char lds[LDS_TOT];

    const int tid = threadIdx.x;
    const int l = tid & 63;
    const int w = tid >> 6;           // wave 0..7
    const int wrow = (w >> 2) * 128;  // 0 or 128
    const int wcol = (w & 3) * 64;    // 0,64,128,192
    const int lr = l & 15;            // row/col within 16-block
    const int kq = l >> 4;            // k-quarter
    const int swz = lr & 7;

    // staging geometry: per wave-chunk of 1KB = 8 rows x 128B (one K-half)
    const int rsub = l >> 3;          // row within 8-row chunk
    const int psl  = l & 7;           // phys slot
    const int srcsw = (psl ^ rsub) << 4;   // swizzled byte offset within half

    int it = blockIdx.x;
    if (it >= ntiles) return;

    int bi, bj;
    decode_tile(it, T, bi, bj);

    // stage(b0): first K-half of first tile
    {
        const char* gA = (const char*)(Z16 + (size_t)bi * TB * TD);
        const char* gB = (const char*)(Z16 + (size_t)bj * TB * TD);
#pragma unroll
        for (int q = 0; q < 4; ++q) {
            const int chunk = w * 4 + q;
            const int row = chunk * 8 + rsub;
            gload16(gA + (size_t)row * 256 + srcsw, lds + LA0 + chunk * 1024);
            gload16(gB + (size_t)row * 256 + srcsw, lds + LB0 + chunk * 1024);
        }
    }

    while (true) {
        // ---- issue stage(b1): second K-half of current tile, + En slices
        {
            const char* gA = (const char*)(Z16 + (size_t)bi * TB * TD);
            const char* gB = (const char*)(Z16 + (size_t)bj * TB * TD);
#pragma unroll
            for (int q = 0; q < 4; ++q) {
                const int chunk = w * 4 + q;
                const int row = chunk * 8 + rsub;
                gload16(gA + (size_t)row * 256 + 128 + srcsw, lds + LA1 + chunk * 1024);
                gload16(gB + (size_t)row * 256 + 128 + srcsw, lds + LB1 + chunk * 1024);
            }
            if (w == 0) gload16(En + (size_t)bi * TB + l * 4, lds + LEA);
            if (w == 1) gload16(En + (size_t)bj * TB + l * 4, lds + LEB);
        }
        // ---- B1: wait b0(cur) staged (b1+En stay in flight)
        if (w < 2) asm volatile("s_waitcnt vmcnt(9)" ::: "memory");
        else       asm volatile("s_waitcnt vmcnt(8)" ::: "memory");
        SCHEDB();
        __builtin_amdgcn_s_barrier();
        SCHEDB();

        // ---- GEMM on K-half 0 (peeled zero-C on kk=0)
        f32x4 acc[8][4];
        const f32x4 zero4 = {0.f, 0.f, 0.f, 0.f};
        __builtin_amdgcn_s_setprio(1);
#pragma unroll
        for (int kk = 0; kk < 2; ++kk) {
            const int soff = ((kk * 4 + kq) ^ swz) << 4;
            half8 bf[4];
#pragma unroll
            for (int j = 0; j < 4; ++j)
                bf[j] = *reinterpret_cast<const half8*>(lds + LB0 + (wcol + j * 16 + lr) * 128 + soff);
#pragma unroll
            for (int i = 0; i < 8; ++i) {
                half8 af = *reinterpret_cast<const half8*>(lds + LA0 + (wrow + i * 16 + lr) * 128 + soff);
#pragma unroll
                for (int j = 0; j < 4; ++j)
                    acc[i][j] = __builtin_amdgcn_mfma_f32_16x16x32_f16(
                        af, bf[j], (kk == 0) ? zero4 : acc[i][j], 0, 0, 0);
            }
        }
        __builtin_amdgcn_s_setprio(0);

        // ---- B2: all waves done reading buf0 -> safe to restage it
        FENCE();
        __builtin_amdgcn_s_barrier();
        SCHEDB();

        // ---- issue stage(b0) of NEXT tile
        const int itn = it + GRID;
        const bool more = (itn < ntiles);
        int bin = bi, bjn = bj;
        if (more) {
            decode_tile(itn, T, bin, bjn);
            const char* gA = (const char*)(Z16 + (size_t)bin * TB * TD);
            const char* gB = (const char*)(Z16 + (size_t)bjn * TB * TD);
#pragma unroll
            for (int q = 0; q < 4; ++q) {
                const int chunk = w * 4 + q;
                const int row = chunk * 8 + rsub;
                gload16(gA + (size_t)row * 256 + srcsw, lds + LA0 + chunk * 1024);
                gload16(gB + (size_t)row * 256 + srcsw, lds + LB0 + chunk * 1024);
            }
        }
        // ---- B3: wait b1(cur)+En (next-tile b0 stays in flight)
        if (more) asm volatile("s_waitcnt vmcnt(8)" ::: "memory");
        else      asm volatile("s_waitcnt vmcnt(0)" ::: "memory");
        SCHEDB();
        __builtin_amdgcn_s_barrier();
        SCHEDB();

        // ---- GEMM on K-half 1
        __builtin_amdgcn_s_setprio(1);
#pragma unroll
        for (int kk = 0; kk < 2; ++kk) {
            const int soff = ((kk * 4 + kq) ^ swz) << 4;
            half8 bf[4];
#pragma unroll
            for (int j = 0; j < 4; ++j)
                bf[j] = *reinterpret_cast<const half8*>(lds + LB1 + (wcol + j * 16 + lr) * 128 + soff);
#pragma unroll
            for (int i = 0; i < 8; ++i) {
                half8 af = *reinterpret_cast<const half8*>(lds + LA1 + (wrow + i * 16 + lr) * 128 + soff);
#pragma unroll
                for (int j = 0; j < 4; ++j)
                    acc[i][j] = __builtin_amdgcn_mfma_f32_16x16x32_f16(af, bf[j], acc[i][j], 0, 0, 0);
            }
        }
        __builtin_amdgcn_s_setprio(0);

        // ---- epilogue: K = Ei * Ej * exp2(M2C2 * dot)
        float Ej[4];
#pragma unroll
        for (int j = 0; j < 4; ++j)
            Ej[j] = *reinterpret_cast<const float*>(lds + LEB + (wcol + j * 16 + lr) * 4);
        f32x4 EiV[8];
#pragma unroll
        for (int i = 0; i < 8; ++i)
            EiV[i] = *reinterpret_cast<const f32x4*>(lds + LEA + (wrow + i * 16 + kq * 4) * 4);

        float s = 0.f;
#pragma unroll
        for (int j = 0; j < 4; ++j) {
            float sj0 = 0.f, sj1 = 0.f;
#pragma unroll
            for (int i = 0; i < 8; ++i) {
#pragma unroll
                for (int r = 0; r < 4; ++r) {
                    float e = EXP2F(M2C2f * acc[i][j][r]);
                    if (r & 1) sj1 = fmaf(EiV[i][r], e, sj1);
                    else       sj0 = fmaf(EiV[i][r], e, sj0);
                }
            }
            s = fmaf(Ej[j], sj0 + sj1, s);
        }

        // ---- block reduce -> double partial for this tile
#pragma unroll
        for (int off = 32; off > 0; off >>= 1) s += __shfl_down(s, off, 64);
        if (l == 0) *reinterpret_cast<float*>(lds + LRED + w * 4) = s;
        asm volatile("s_waitcnt lgkmcnt(0)" ::: "memory");
        SCHEDB();
        __builtin_amdgcn_s_barrier();
        SCHEDB();
        if (tid == 0) {
            const float* sred = reinterpret_cast<const float*>(lds + LRED);
            float bs = 0.f;
#pragma unroll
            for (int q = 0; q < 8; ++q) bs += sred[q];
            double wa = (bi * TB < n) ? (1.0 / (double)n) : (-1.0 / (double)m);
            double wb = (bj * TB < n) ? (1.0 / (double)n) : (-1.0 / (double)m);
            double wgt = wa * wb * ((bi == bj) ? 1.0 : 2.0);
            partials[it] = wgt * (double)bs;
        }

        if (!more) break;
        it = itn; bi = bin; bj = bjn;
    }
}

// ---------------------------------------------------------------------------
// Fallback fp32 path (round-1, proven): used only if ws/shape unsuitable
// ---------------------------------------------------------------------------
__global__ __launch_bounds__(256) void norms_kernel(const float* __restrict__ X,
                                                    const float* __restrict__ Y,
                                                    int n, int tot,
                                                    float* __restrict__ norms) {
    int r = blockIdx.x * 256 + threadIdx.x;
    if (r >= tot) return;
    const float* row = (r < n) ? (X + (size_t)r * TD) : (Y + (size_t)(r - n) * TD);
    float s = 0.f;
#pragma unroll
    for (int k = 0; k < TD; k += 4) {
        float4 v = *reinterpret_cast<const float4*>(row + k);
        s = fmaf(v.x, v.x, s); s = fmaf(v.y, v.y, s);
        s = fmaf(v.z, v.z, s); s = fmaf(v.w, v.w, s);
    }
    norms[r] = s;
}

__global__ __launch_bounds__(256, 2) void mmd_tile_kernel(const float* __restrict__ X,
                                                          const float* __restrict__ Y,
                                                          const float* __restrict__ norms,
                                                          double* __restrict__ partials,
                                                          int n, int m, int T) {
    __shared__ float sA[TD][BT];
    __shared__ float sB[TD][BT];
    __shared__ float sredf[4];

    const int t = blockIdx.x;
    int bi, bj;
    decode_tile(t, T, bi, bj);

    const int tid = threadIdx.x;
    {
        const int row = tid & 63;
        const int qb  = tid >> 6;
        const int ra = bi * BT + row;
        const int rb = bj * BT + row;
        const float* Arow = (ra < n) ? (X + (size_t)ra * TD) : (Y + (size_t)(ra - n) * TD);
        const float* Brow = (rb < n) ? (X + (size_t)rb * TD) : (Y + (size_t)(rb - n) * TD);
#pragma unroll
        for (int i = 0; i < 8; ++i) {
            const int q = qb + 4 * i;
            float4 va = *reinterpret_cast<const float4*>(Arow + 4 * q);
            sA[4 * q + 0][row] = va.x; sA[4 * q + 1][row] = va.y;
            sA[4 * q + 2][row] = va.z; sA[4 * q + 3][row] = va.w;
            float4 vb = *reinterpret_cast<const float4*>(Brow + 4 * q);
            sB[4 * q + 0][row] = vb.x; sB[4 * q + 1][row] = vb.y;
            sB[4 * q + 2][row] = vb.z; sB[4 * q + 3][row] = vb.w;
        }
    }
    __syncthreads();

    const int tx = tid & 15;
    const int ty = tid >> 4;
    float acc[4][4];
#pragma unroll
    for (int i = 0; i < 4; ++i)
#pragma unroll
        for (int j = 0; j < 4; ++j) acc[i][j] = 0.f;

#pragma unroll 16
    for (int k = 0; k < TD; ++k) {
        float4 a = *reinterpret_cast<const float4*>(&sA[k][ty * 4]);
        float4 b = *reinterpret_cast<const float4*>(&sB[k][tx * 4]);
        const float av[4] = {a.x, a.y, a.z, a.w};
        const float bv[4] = {b.x, b.y, b.z, b.w};
#pragma unroll
        for (int i = 0; i < 4; ++i)
#pragma unroll
            for (int j = 0; j < 4; ++j)
                acc[i][j] = fmaf(av[i], bv[j], acc[i][j]);
    }

    float nA[4], nB[4];
#pragma unroll
    for (int i = 0; i < 4; ++i) nA[i] = norms[bi * BT + ty * 4 + i];
#pragma unroll
    for (int j = 0; j < 4; ++j) nB[j] = norms[bj * BT + tx * 4 + j];

    const float cexp = -0.005f;
    float s = 0.f;
#pragma unroll
    for (int i = 0; i < 4; ++i)
#pragma unroll
        for (int j = 0; j < 4; ++j) {
            float d2 = fmaxf(nA[i] + nB[j] - 2.f * acc[i][j], 0.f);
            s += __expf(d2 * cexp);
        }

#pragma unroll
    for (int off = 32; off > 0; off >>= 1) s += __shfl_down(s, off, 64);
    if ((tid & 63) == 0) sredf[tid >> 6] = s;
    __syncthreads();
    if (tid == 0) {
        double wa = (bi * BT < n) ? (1.0 / (double)n) : (-1.0 / (double)m);
        double wb = (bj * BT < n) ? (1.0 / (double)n) : (-1.0 / (double)m);
        double wgt = wa * wb * ((bi == bj) ? 1.0 : 2.0);
        partials[t] = wgt * (double)(sredf[0] + sredf[1] + sredf[2] + sredf[3]);
    }
}

// ---------------------------------------------------------------------------
__global__ __launch_bounds__(256) void reduce_kernel(const double* __restrict__ partials,
                                                     int npart,
                                                     float* __restrict__ out) {
    __shared__ double sd[256];
    double s = 0.0;
    for (int i = threadIdx.x; i < npart; i += 256) s += partials[i];
    sd[threadIdx.x] = s;
    __syncthreads();
    for (int off = 128; off > 0; off >>= 1) {
        if ((int)threadIdx.x < off) sd[threadIdx.x] += sd[threadIdx.x + off];
        __syncthreads();
    }
    if (threadIdx.x == 0) out[0] = (float)sd[0];
}

// ---------------------------------------------------------------------------
extern "C" void kernel_launch(void* const* d_in, const int* in_sizes, int n_in,
                              void* d_out, int out_size, void* d_ws, size_t ws_size,
                              hipStream_t stream) {
    const float* X = (const float*)d_in[0];
    const float* Y = (const float*)d_in[1];
    float* out = (float*)d_out;

    const int n = in_sizes[0] / TD;
    const int m = in_sizes[1] / TD;
    const int tot = n + m;

    // fp16-MFMA path workspace: Z16 + En + partials
    const size_t z16_bytes = (size_t)tot * TD * 2;
    const size_t en_off    = (z16_bytes + 255) & ~(size_t)255;
    const size_t en_bytes  = (size_t)tot * 4;
    const size_t part_off  = ((en_off + en_bytes) + 255) & ~(size_t)255;
    const int Tm = tot / TB;
    const int npart_m = Tm * (Tm + 1) / 2;
    const size_t needed = part_off + (size_t)npart_m * 8;

    if (ws_size >= needed && (tot % TB) == 0 && (n % TB) == 0) {
        _Float16* Z16 = (_Float16*)d_ws;
        float* En = (float*)((char*)d_ws + en_off);
        double* partials = (double*)((char*)d_ws + part_off);
        cvt_norms_kernel<<<(tot + 3) / 4, 256, 0, stream>>>(X, Y, n, tot, Z16, En);
        int grid = (npart_m < GRID) ? npart_m : GRID;
        mmd_pipe_kernel<<<grid, 512, 0, stream>>>(Z16, En, partials, n, m, Tm, npart_m);
        reduce_kernel<<<1, 256, 0, stream>>>(partials, npart_m, out);
    } else {
        const int T = tot / BT;
        const int npart = T * (T + 1) / 2;
        float* norms = (float*)d_ws;
        double* partials = (double*)((char*)d_ws + (((size_t)tot * 4 + 255) & ~(size_t)255));
        norms_kernel<<<(tot + 255) / 256, 256, 0, stream>>>(X, Y, n, tot, norms);
        mmd_tile_kernel<<<npart, 256, 0, stream>>>(X, Y, norms, partials, n, m, T);
        reduce_kernel<<<1, 256, 0, stream>>>(partials, npart, out);
    }
}